// Round 10
// baseline (509.882 us; speedup 1.0000x reference)
//
#include <hip/hip_runtime.h>

// ArDCA loss: loss = -sum_{m,i} W[m] * log_softmax(h[i,:] + sum_{j<i} J[i,j,:,X[m,j]])[X[m,i]]
//             + 1e-6 * sum h^2 + 1e-4 * sum_{j<i} J^2
// M=8192, L=256, Q=21. Output: single fp32 scalar.
//
// R14: 24-B rows (3 f16 + 18 fp8), 3x ds_read_b64 gather.
// Bookkeeping from R13: dur_us carries a constant ~105us harness overhead
// (verified across R4/R7/R11/R13); kernel-side is pair 322 + transcode ~60.
// R13 falsified the "coprime stride = conflict-free" model (conflicts only
// 8.04e7 -> 6.18e7); every layout measured leaves 2-4 extra cyc/read, best
// was 24-B stride b64 (R7: 2.3/read). This round: cut LDS instrs 4->3 and
// take the best-measured conflict stride.
//  - Row payload 24 B: f16 a0,a1,a2 (6 B) + fp8(x256) a3..a20 (18 B).
//    Pair block 21*24=504 -> 512 B. JC=16, CHUNKB=8192, 2 gload16/thread.
//    LDS 2x8KB -> ~8 blocks/CU (occupancy up from 60%).
//  - Gather: 3x ds_read_b64 at 24-B stride; decode 9 cvt_pk_f32_fp8 +
//    9 pk_add_f32 + 1 pk_add_f16 + 1 f16 add. All-fp8 passed absmax 0
//    (R7/R9), so 18-of-21 fp8 is accuracy-safe.
//  - Discriminator round: pair ~320 + VALU>=70% -> VALU-inflation wall;
//    pair ~320 + VALU~50 + low conflicts -> chunk-latency wall.
// Transcode: R13's wave-per-pair structure (~60us), re-mapped to 512-B
// blocks (2 u32 slots/lane). ws: 32640*512 = 16.7 MB.

#define M_SEQ 8192
#define L_POS 256
#define Q_SYM 21
#define QQ    441
#define JC    16
#define NPAIR 32640                  // 256*255/2
#define PAIRB 512                    // padded bytes per (i,j) pair in J8
#define ROWB  24                     // bytes per row b (24 payload)
#define CHUNKB (JC * PAIRB)          // 8192 B staged per chunk
#define PPW   4                      // pairs per wave (transcode)
#define PPB   16                     // pairs per block = 4 waves * PPW

typedef _Float16 h2 __attribute__((ext_vector_type(2)));
typedef float f32x2 __attribute__((ext_vector_type(2)));

__device__ __forceinline__ h2 as_h2(unsigned int u) {
    union { unsigned int u; h2 h; } c; c.u = u; return c.h;
}

__device__ __forceinline__ float wave_block_reduce(float v, float* red, int tid) {
    #pragma unroll
    for (int off = 32; off > 0; off >>= 1) v += __shfl_down(v, off, 64);
    if ((tid & 63) == 0) red[tid >> 6] = v;
    __syncthreads();
    return red[0] + red[1] + red[2] + red[3];
}

__device__ __forceinline__ void gload16(const void* g, void* l) {
    __builtin_amdgcn_global_load_lds(
        (const __attribute__((address_space(1))) unsigned int*)g,
        (__attribute__((address_space(3))) unsigned int*)l, 16, 0, 0);
}

__global__ void zero_out(float* __restrict__ out) { out[0] = 0.0f; }

// ---- Kernel A: J[i][j][a][b] (fp32, lower tri) -> J8[pair] 512-B blocks:
//      row b at b*24: f16 a0..a2 + fp8(x256) a3..a20. One pair per wave,
//      barrier-free: coalesced load -> LDS transpose -> coalesced store.
__global__ __launch_bounds__(256) void transcode_kernel(const float* __restrict__ J,
                                                        const float* __restrict__ h,
                                                        unsigned char* __restrict__ J8,
                                                        float* __restrict__ out) {
    __shared__ float raw[4][448];              // per-wave staging (441 used)
    __shared__ float red[4];
    const int tid  = threadIdx.x;
    const int wid  = tid >> 6;
    const int lane = tid & 63;

    int p = blockIdx.x * PPB + wid * PPW;      // first pair for this wave
    int ii = (int)((1.0f + sqrtf((float)(8 * p + 1))) * 0.5f);
    while (ii * (ii - 1) / 2 > p) --ii;
    while ((ii + 1) * ii / 2 <= p) ++ii;
    int jj = p - ii * (ii - 1) / 2;

    const float S = 256.0f;
    float rs = 0.0f;
    float* mybuf = raw[wid];

    for (int t = 0; t < PPW; ++t, ++p) {
        const float* src = J + ((size_t)ii * L_POS + jj) * QQ;
        #pragma unroll
        for (int r = 0; r < 7; ++r) {          // coalesced stage: 7 dw/lane
            int idx = lane + 64 * r;
            if (idx < QQ) {
                float v = src[idx];
                rs += v * v;                   // each lower-tri value once
                mybuf[idx] = v;
            }
        }
        asm volatile("s_waitcnt lgkmcnt(0)" ::: "memory");
        __builtin_amdgcn_wave_barrier();

        // ---- each lane encodes 2 u32 slots; coalesced 512-B store
        unsigned int* dst = (unsigned int*)(J8 + (size_t)p * PAIRB);
        #pragma unroll
        for (int r = 0; r < 2; ++r) {
            int s = lane + 64 * r;             // 0..127
            int b = s / 6, g = s - 6 * b;      // row, u32 slot within row
            unsigned int w = 0u;
            if (b < Q_SYM) {
                const float* col = mybuf + b;  // col[a*21]
                if (g == 0) {                  // f16 a0 | f16 a1
                    union { _Float16 h[2]; unsigned int u; } cv;
                    cv.h[0] = (_Float16)col[0];
                    cv.h[1] = (_Float16)col[Q_SYM];
                    w = cv.u;
                } else if (g == 1) {           // f16 a2 | fp8 a3 | fp8 a4
                    union { _Float16 h[2]; unsigned int u; } cv;
                    cv.h[0] = (_Float16)col[2 * Q_SYM]; cv.h[1] = (_Float16)0.f;
                    int e = __builtin_amdgcn_cvt_pk_fp8_f32(col[3 * Q_SYM] * S,
                                                            col[4 * Q_SYM] * S, 0, false);
                    w = (cv.u & 0xffffu) | (((unsigned int)e & 0xffffu) << 16);
                } else {                       // 4 fp8: a(4g-3)..a(4g)
                    int a0 = 4 * g - 3;
                    int e = __builtin_amdgcn_cvt_pk_fp8_f32(col[(a0    ) * Q_SYM] * S,
                                                            col[(a0 + 1) * Q_SYM] * S, 0, false);
                    e     = __builtin_amdgcn_cvt_pk_fp8_f32(col[(a0 + 2) * Q_SYM] * S,
                                                            col[(a0 + 3) * Q_SYM] * S, e, true);
                    w = (unsigned int)e;
                }
            }
            dst[s] = w;
        }
        __builtin_amdgcn_wave_barrier();       // raw[] reuse (DS in-order per wave)
        ++jj; if (jj == ii) { jj = 0; ++ii; }
    }

    float acc = 1e-4f * rs;
    if (blockIdx.x == 0) {                     // fold h^2 once
        float hs = 0.0f;
        for (int t = tid; t < L_POS * Q_SYM; t += 256) { float v = h[t]; hs += v * v; }
        acc += 1e-6f * hs;
    }
    float tot = wave_block_reduce(acc, red, tid);
    if (tid == 0) atomicAdd(out, tot);
}

// ---- Kernel B: one block per (m-chunk of 256, i). Each thread owns one m.
__global__ __launch_bounds__(256) void pair_nll_kernel(const int* __restrict__ X,
                                                       const float* __restrict__ W,
                                                       const float* __restrict__ h,
                                                       const unsigned char* __restrict__ J8,
                                                       float* __restrict__ out) {
    __shared__ unsigned char JL[2][CHUNKB];    // 2 x 8192 B
    __shared__ float red[4];

    const int tid = threadIdx.x;
    const int i  = blockIdx.y;
    const int m  = blockIdx.x * 256 + tid;
    const int* xrow = X + (size_t)m * L_POS;
    const unsigned char* jbase = J8 + ((size_t)i * (i - 1) / 2) * PAIRB;

    h2 accF;  accF.x = (_Float16)0.f; accF.y = (_Float16)0.f;   // a0,a1
    _Float16 acc2 = (_Float16)0.f;                               // a2
    f32x2 accB[9];                                               // a3..a20
    #pragma unroll
    for (int k = 0; k < 9; ++k) { accB[k].x = 0.f; accB[k].y = 0.f; }

    const int nch = (i + JC - 1) / JC;
    const int wbase = (tid >> 6) << 10;        // wave-uniform LDS base offset

    if (nch > 0) {                             // issue chunk 0 (2 issues/thread)
        const unsigned char* g = jbase + tid * 16;
        gload16(g,        &JL[0][wbase]);
        gload16(g + 4096, &JL[0][4096 + wbase]);
    }
    __syncthreads();                           // implicit vmcnt(0): chunk 0 arrived

    for (int k = 0; k < nch; ++k) {
        const int j0 = k * JC;

        // ---- issue chunk k+1 into the other buffer (in flight over gather)
        if (k + 1 < nch) {
            const unsigned char* g = jbase + (size_t)(k + 1) * CHUNKB + tid * 16;
            unsigned char* l = &JL[(k + 1) & 1][wbase];
            gload16(g,        l);
            gload16(g + 4096, l + 4096);
        }

        // ---- this thread's 16 X values (block-uniform guards keep loads in-bounds)
        int4 xA = *(const int4*)(xrow + j0);
        int4 xB = make_int4(0,0,0,0), xC = make_int4(0,0,0,0), xD = make_int4(0,0,0,0);
        if (j0 + 4  < i) xB = *(const int4*)(xrow + j0 + 4);
        if (j0 + 8  < i) xC = *(const int4*)(xrow + j0 + 8);
        if (j0 + 12 < i) xD = *(const int4*)(xrow + j0 + 12);
        int xv[JC] = {xA.x, xA.y, xA.z, xA.w, xB.x, xB.y, xB.z, xB.w,
                      xC.x, xC.y, xC.z, xC.w, xD.x, xD.y, xD.z, xD.w};

        const unsigned char* buf = JL[k & 1];
        #pragma unroll
        for (int jc = 0; jc < JC; ++jc) {
            if (j0 + jc < i) {                 // block-uniform guard
                int b = xv[jc];
                const unsigned char* rb = buf + (jc << 9) + b * ROWB;
                uint2 q0 = *(const uint2*)(rb);        // f16 a0,a1 | f16 a2 + fp8 a3,a4
                uint2 q1 = *(const uint2*)(rb + 8);    // fp8 a5..a12
                uint2 q2 = *(const uint2*)(rb + 16);   // fp8 a13..a20
                accF    += as_h2(q0.x);
                acc2    += as_h2(q0.y).x;
                accB[0] += __builtin_amdgcn_cvt_pk_f32_fp8((int)q0.y, true);
                accB[1] += __builtin_amdgcn_cvt_pk_f32_fp8((int)q1.x, false);
                accB[2] += __builtin_amdgcn_cvt_pk_f32_fp8((int)q1.x, true);
                accB[3] += __builtin_amdgcn_cvt_pk_f32_fp8((int)q1.y, false);
                accB[4] += __builtin_amdgcn_cvt_pk_f32_fp8((int)q1.y, true);
                accB[5] += __builtin_amdgcn_cvt_pk_f32_fp8((int)q2.x, false);
                accB[6] += __builtin_amdgcn_cvt_pk_f32_fp8((int)q2.x, true);
                accB[7] += __builtin_amdgcn_cvt_pk_f32_fp8((int)q2.y, false);
                accB[8] += __builtin_amdgcn_cvt_pk_f32_fp8((int)q2.y, true);
            }
        }

        // one barrier per chunk: drains vmcnt(0) (chunk k+1 arrived) and joins
        // all waves' reads of buf[k&1] before iter k+2 overwrites it.
        __syncthreads();
    }

    // ---- logits = h[i,:] + pair ; log-softmax ; pick gold = X[m,i]
    const float* hrow = h + i * Q_SYM;
    const float INV = 0.00390625f;             // 1/256: undo fp8 encode pre-scale
    float logits[Q_SYM];
    logits[0] = hrow[0] + (float)accF.x;
    logits[1] = hrow[1] + (float)accF.y;
    logits[2] = hrow[2] + (float)acc2;
    #pragma unroll
    for (int t = 0; t < 9; ++t) {
        logits[3 + 2 * t] = hrow[3 + 2 * t] + accB[t].x * INV;
        logits[4 + 2 * t] = hrow[4 + 2 * t] + accB[t].y * INV;
    }

    float mx = -3.4e38f;
    #pragma unroll
    for (int a = 0; a < Q_SYM; ++a) mx = fmaxf(mx, logits[a]);
    float s = 0.0f;
    #pragma unroll
    for (int a = 0; a < Q_SYM; ++a) s += __expf(logits[a] - mx);
    int g = xrow[i];
    float gold = 0.0f;
    #pragma unroll
    for (int a = 0; a < Q_SYM; ++a) gold = (a == g) ? logits[a] : gold;
    float logp = gold - mx - __logf(s);
    float v = -W[m] * logp;

    float tot = wave_block_reduce(v, red, tid);
    if (tid == 0) atomicAdd(out, tot);
}

extern "C" void kernel_launch(void* const* d_in, const int* in_sizes, int n_in,
                              void* d_out, int out_size, void* d_ws, size_t ws_size,
                              hipStream_t stream) {
    const int*   X = (const int*)d_in[0];
    const float* W = (const float*)d_in[1];
    const float* h = (const float*)d_in[2];
    const float* J = (const float*)d_in[3];
    float* out = (float*)d_out;
    unsigned char* J8 = (unsigned char*)d_ws;  // needs 32640*512 + pad = 16.8 MB

    hipLaunchKernelGGL(zero_out, dim3(1), dim3(1), 0, stream, out);
    hipLaunchKernelGGL(transcode_kernel, dim3(NPAIR / PPB), dim3(256), 0, stream,
                       J, h, J8, out);
    dim3 grid(M_SEQ / 256, L_POS);
    hipLaunchKernelGGL(pair_nll_kernel, grid, dim3(256), 0, stream, X, W, h, J8, out);
}

// Round 11
// 463.747 us; speedup vs baseline: 1.0995x; 1.0995x over previous
//
#include <hip/hip_runtime.h>

// ArDCA loss: loss = -sum_{m,i} W[m] * log_softmax(h[i,:] + sum_{j<i} J[i,j,:,X[m,j]])[X[m,i]]
//             + 1e-6 * sum h^2 + 1e-4 * sum_{j<i} J^2
// M=8192, L=256, Q=21. Output: single fp32 scalar.
//
// R15: bf8(e5m2) rows with bit-op decode — breaks the LDS/VALU double wall.
// Round history: f16 variants (R10/R13) wall on LDS (~630k cyc/CU, 322-330us);
// fp8-e4m3 variants (R9/R14) wall on VALU (cvt_pk_f32_fp8 measured ~quarter
// rate: 198 cyc/wave-j at 93% VALUBusy). KEY: e5m2 bf8 IS f16's top byte.
// Decode = (w<<8)&0xFF00FF00 -> f16 pair (a_even), w&0xFF00FF00 -> (a_odd):
// 3 full-rate bit-ops + 2 pk_add_f16 per dword. No cvt, no scale (e5m2 min
// normal 6e-5 << |J|~0.01; subnormals below that are absolutely negligible).
//  - Rows: 21 bf8 + 3 pad = 24 B; pair block 512 B; JC=16; CHUNKB=8192;
//    2x gload16/thread/chunk; LDS 2x8KB -> ~8 blocks/CU.
//  - Gather: 3x ds_read_b64 @24-B stride (R14-measured ~10 cyc/read w/
//    conflicts) -> LDS ~490k cyc/CU = 204us; VALU ~75 cyc/wave-j = 128us.
//  - Accumulate f16 pairs even/odd interleaved: accE[k]=(a4k,a4k+2),
//    accO[k]=(a4k+1,a4k+3), acc20; epilogue un-interleaves.
// Encode (transcode): bf8 = (f16bits + 0x80) >> 8 (RNE-ish, carry into exp
// is correct at these magnitudes). Predicted: pair 240-265us, VALU 45-55%,
// total ~410-430. absmax risk: e5m2 err 2x e4m3 (which passed 0 thrice);
// fallback = 11f16+10bf8/32B. ws: 32640*512 = 16.7 MB.

#define M_SEQ 8192
#define L_POS 256
#define Q_SYM 21
#define QQ    441
#define JC    16
#define NPAIR 32640                  // 256*255/2
#define PAIRB 512                    // padded bytes per (i,j) pair in J8
#define ROWB  24                     // bytes per row b (21 payload + 3 pad)
#define CHUNKB (JC * PAIRB)          // 8192 B staged per chunk
#define PPW   4                      // pairs per wave (transcode)
#define PPB   16                     // pairs per block = 4 waves * PPW

typedef _Float16 h2 __attribute__((ext_vector_type(2)));

__device__ __forceinline__ h2 as_h2(unsigned int u) {
    union { unsigned int u; h2 h; } c; c.u = u; return c.h;
}

__device__ __forceinline__ float wave_block_reduce(float v, float* red, int tid) {
    #pragma unroll
    for (int off = 32; off > 0; off >>= 1) v += __shfl_down(v, off, 64);
    if ((tid & 63) == 0) red[tid >> 6] = v;
    __syncthreads();
    return red[0] + red[1] + red[2] + red[3];
}

__device__ __forceinline__ void gload16(const void* g, void* l) {
    __builtin_amdgcn_global_load_lds(
        (const __attribute__((address_space(1))) unsigned int*)g,
        (__attribute__((address_space(3))) unsigned int*)l, 16, 0, 0);
}

// f32 -> bf8(e5m2) byte: truncate f16 to top byte with round-to-nearest.
__device__ __forceinline__ unsigned int bf8enc(float v) {
    union { _Float16 h; unsigned short u; } c;
    c.h = (_Float16)v;
    return (unsigned int)((unsigned short)(c.u + (unsigned short)0x80) >> 8) & 0xffu;
}

__global__ void zero_out(float* __restrict__ out) { out[0] = 0.0f; }

// ---- Kernel A: J[i][j][a][b] (fp32, lower tri) -> J8[pair] 512-B blocks:
//      row b at b*24, bytes 0..20 = bf8(J[..,a,b]) for a=0..20. One pair per
//      wave, barrier-free: coalesced load -> LDS transpose -> coalesced store.
__global__ __launch_bounds__(256) void transcode_kernel(const float* __restrict__ J,
                                                        const float* __restrict__ h,
                                                        unsigned char* __restrict__ J8,
                                                        float* __restrict__ out) {
    __shared__ float raw[4][448];              // per-wave staging (441 used)
    __shared__ float red[4];
    const int tid  = threadIdx.x;
    const int wid  = tid >> 6;
    const int lane = tid & 63;

    int p = blockIdx.x * PPB + wid * PPW;      // first pair for this wave
    int ii = (int)((1.0f + sqrtf((float)(8 * p + 1))) * 0.5f);
    while (ii * (ii - 1) / 2 > p) --ii;
    while ((ii + 1) * ii / 2 <= p) ++ii;
    int jj = p - ii * (ii - 1) / 2;

    float rs = 0.0f;
    float* mybuf = raw[wid];

    for (int t = 0; t < PPW; ++t, ++p) {
        const float* src = J + ((size_t)ii * L_POS + jj) * QQ;
        #pragma unroll
        for (int r = 0; r < 7; ++r) {          // coalesced stage: 7 dw/lane
            int idx = lane + 64 * r;
            if (idx < QQ) {
                float v = src[idx];
                rs += v * v;                   // each lower-tri value once
                mybuf[idx] = v;
            }
        }
        asm volatile("s_waitcnt lgkmcnt(0)" ::: "memory");
        __builtin_amdgcn_wave_barrier();

        // ---- each lane encodes 2 u32 slots; coalesced 512-B store
        // slot s = b*6+g: g<5 -> bf8 of a=4g..4g+3; g==5 -> bf8(a20)+pad.
        unsigned int* dst = (unsigned int*)(J8 + (size_t)p * PAIRB);
        #pragma unroll
        for (int r = 0; r < 2; ++r) {
            int s = lane + 64 * r;             // 0..127
            int b = s / 6, g = s - 6 * b;
            unsigned int w = 0u;
            if (b < Q_SYM) {
                const float* col = mybuf + b;  // col[a*21]
                if (g < 5) {
                    int a0 = 4 * g;
                    w =  bf8enc(col[(a0    ) * Q_SYM])
                      | (bf8enc(col[(a0 + 1) * Q_SYM]) << 8)
                      | (bf8enc(col[(a0 + 2) * Q_SYM]) << 16)
                      | (bf8enc(col[(a0 + 3) * Q_SYM]) << 24);
                } else {                       // g == 5
                    w = bf8enc(col[20 * Q_SYM]);
                }
            }
            dst[s] = w;
        }
        __builtin_amdgcn_wave_barrier();       // raw[] reuse (DS in-order per wave)
        ++jj; if (jj == ii) { jj = 0; ++ii; }
    }

    float acc = 1e-4f * rs;
    if (blockIdx.x == 0) {                     // fold h^2 once
        float hs = 0.0f;
        for (int t = tid; t < L_POS * Q_SYM; t += 256) { float v = h[t]; hs += v * v; }
        acc += 1e-6f * hs;
    }
    float tot = wave_block_reduce(acc, red, tid);
    if (tid == 0) atomicAdd(out, tot);
}

// ---- Kernel B: one block per (m-chunk of 256, i). Each thread owns one m.
__global__ __launch_bounds__(256) void pair_nll_kernel(const int* __restrict__ X,
                                                       const float* __restrict__ W,
                                                       const float* __restrict__ h,
                                                       const unsigned char* __restrict__ J8,
                                                       float* __restrict__ out) {
    __shared__ unsigned char JL[2][CHUNKB];    // 2 x 8192 B
    __shared__ float red[4];

    const int tid = threadIdx.x;
    const int i  = blockIdx.y;
    const int m  = blockIdx.x * 256 + tid;
    const int* xrow = X + (size_t)m * L_POS;
    const unsigned char* jbase = J8 + ((size_t)i * (i - 1) / 2) * PAIRB;

    const unsigned int MASK = 0xFF00FF00u;
    h2 accE[5], accO[5];                       // (a4k, a4k+2), (a4k+1, a4k+3)
    #pragma unroll
    for (int k = 0; k < 5; ++k) {
        accE[k].x = (_Float16)0.f; accE[k].y = (_Float16)0.f;
        accO[k].x = (_Float16)0.f; accO[k].y = (_Float16)0.f;
    }
    _Float16 acc20 = (_Float16)0.f;

    const int nch = (i + JC - 1) / JC;
    const int wbase = (tid >> 6) << 10;        // wave-uniform LDS base offset

    if (nch > 0) {                             // issue chunk 0 (2 issues/thread)
        const unsigned char* g = jbase + tid * 16;
        gload16(g,        &JL[0][wbase]);
        gload16(g + 4096, &JL[0][4096 + wbase]);
    }
    __syncthreads();                           // implicit vmcnt(0): chunk 0 arrived

    for (int k = 0; k < nch; ++k) {
        const int j0 = k * JC;

        // ---- issue chunk k+1 into the other buffer (in flight over gather)
        if (k + 1 < nch) {
            const unsigned char* g = jbase + (size_t)(k + 1) * CHUNKB + tid * 16;
            unsigned char* l = &JL[(k + 1) & 1][wbase];
            gload16(g,        l);
            gload16(g + 4096, l + 4096);
        }

        // ---- this thread's 16 X values (block-uniform guards keep loads in-bounds)
        int4 xA = *(const int4*)(xrow + j0);
        int4 xB = make_int4(0,0,0,0), xC = make_int4(0,0,0,0), xD = make_int4(0,0,0,0);
        if (j0 + 4  < i) xB = *(const int4*)(xrow + j0 + 4);
        if (j0 + 8  < i) xC = *(const int4*)(xrow + j0 + 8);
        if (j0 + 12 < i) xD = *(const int4*)(xrow + j0 + 12);
        int xv[JC] = {xA.x, xA.y, xA.z, xA.w, xB.x, xB.y, xB.z, xB.w,
                      xC.x, xC.y, xC.z, xC.w, xD.x, xD.y, xD.z, xD.w};

        const unsigned char* buf = JL[k & 1];
        #pragma unroll
        for (int jc = 0; jc < JC; ++jc) {
            if (j0 + jc < i) {                 // block-uniform guard
                int b = xv[jc];
                const unsigned char* rb = buf + (jc << 9) + b * ROWB;
                uint2 q0 = *(const uint2*)(rb);        // bf8 a0..a7
                uint2 q1 = *(const uint2*)(rb + 8);    // bf8 a8..a15
                uint2 q2 = *(const uint2*)(rb + 16);   // bf8 a16..a20 + pad
                // decode: (w<<8)&MASK -> f16 pair (a_even); w&MASK -> (a_odd)
                accE[0] += as_h2((q0.x << 8) & MASK);
                accO[0] += as_h2( q0.x       & MASK);
                accE[1] += as_h2((q0.y << 8) & MASK);
                accO[1] += as_h2( q0.y       & MASK);
                accE[2] += as_h2((q1.x << 8) & MASK);
                accO[2] += as_h2( q1.x       & MASK);
                accE[3] += as_h2((q1.y << 8) & MASK);
                accO[3] += as_h2( q1.y       & MASK);
                accE[4] += as_h2((q2.x << 8) & MASK);
                accO[4] += as_h2( q2.x       & MASK);
                acc20   += as_h2((q2.y << 8) & MASK).x;
            }
        }

        // one barrier per chunk: drains vmcnt(0) (chunk k+1 arrived) and joins
        // all waves' reads of buf[k&1] before iter k+2 overwrites it.
        __syncthreads();
    }

    // ---- logits = h[i,:] + pair ; log-softmax ; pick gold = X[m,i]
    const float* hrow = h + i * Q_SYM;
    float logits[Q_SYM];
    #pragma unroll
    for (int k = 0; k < 5; ++k) {
        logits[4 * k]     = hrow[4 * k]     + (float)accE[k].x;
        logits[4 * k + 1] = hrow[4 * k + 1] + (float)accO[k].x;
        logits[4 * k + 2] = hrow[4 * k + 2] + (float)accE[k].y;
        logits[4 * k + 3] = hrow[4 * k + 3] + (float)accO[k].y;
    }
    logits[20] = hrow[20] + (float)acc20;

    float mx = -3.4e38f;
    #pragma unroll
    for (int a = 0; a < Q_SYM; ++a) mx = fmaxf(mx, logits[a]);
    float s = 0.0f;
    #pragma unroll
    for (int a = 0; a < Q_SYM; ++a) s += __expf(logits[a] - mx);
    int g = xrow[i];
    float gold = 0.0f;
    #pragma unroll
    for (int a = 0; a < Q_SYM; ++a) gold = (a == g) ? logits[a] : gold;
    float logp = gold - mx - __logf(s);
    float v = -W[m] * logp;

    float tot = wave_block_reduce(v, red, tid);
    if (tid == 0) atomicAdd(out, tot);
}

extern "C" void kernel_launch(void* const* d_in, const int* in_sizes, int n_in,
                              void* d_out, int out_size, void* d_ws, size_t ws_size,
                              hipStream_t stream) {
    const int*   X = (const int*)d_in[0];
    const float* W = (const float*)d_in[1];
    const float* h = (const float*)d_in[2];
    const float* J = (const float*)d_in[3];
    float* out = (float*)d_out;
    unsigned char* J8 = (unsigned char*)d_ws;  // needs 32640*512 = 16.7 MB

    hipLaunchKernelGGL(zero_out, dim3(1), dim3(1), 0, stream, out);
    hipLaunchKernelGGL(transcode_kernel, dim3(NPAIR / PPB), dim3(256), 0, stream,
                       J, h, J8, out);
    dim3 grid(M_SEQ / 256, L_POS);
    hipLaunchKernelGGL(pair_nll_kernel, grid, dim3(256), 0, stream, X, W, h, J8, out);
}